// Round 13
// baseline (553.312 us; speedup 1.0000x reference)
//
#include <hip/hip_runtime.h>
#include <hip/hip_bf16.h>

#define E_EDGES 500000
#define NENT    100000
#define NREL    237
#define DIM     100
#define TDIM    300
#define TWO_E   1000000
#define BN_EPS  1e-5f
#define PITCH   256        // u16 elems per UEp row (512B): U0 at +0, U1 at +128
#define NB      512        // histogram/scatter blocks
#define CHUNK   977        // ceil(E_EDGES/NB)
#define RSEG    16         // segments per rel in rel-aggregation
#define ECHUNK  391        // entities per scan chunk (256*391 >= NENT)

typedef unsigned short u16;
typedef unsigned int   u32;
typedef unsigned long long u64;

// ---------- ws layout (offsets in floats) ----------
static const size_t OFF_DEG     = 0;         // u32[100000] (zeroed)
static const size_t OFF_CUR     = 100000;    // u32[100000] (zeroed)
static const size_t OFF_S1      = 200000;    // 128 (zeroed)
static const size_t OFF_S2      = 200128;    // 128 (zeroed)
static const size_t OFF_S2R     = 200256;    // 128 (zeroed)
static const size_t OFF_SC      = 200384;    // 128 (zeroed)
static const size_t OFF_SC2     = 200512;    // 128 (zeroed)
static const size_t OFF_CONST   = 200640;    // 64  (zeroed)
static const size_t OFF_RELACC  = 200704;    // 23744 (zeroed)
static const size_t ZERO_END    = 224448;
static const size_t OFF_OFFS    = 224448;    // u32[100001]
static const size_t OFF_ROFF    = 324464;    // u32[240]
static const size_t OFF_RELCNTF = 324704;    // float[256]
static const size_t OFF_BHIST   = 324960;    // u32[NB*256]
static const size_t OFF_RBASE   = 456032;    // u32[237*NB]
static const size_t OFF_PART    = 577376;    // u32[256]
static const size_t OFF_BASE    = 577632;    // u32[256]
static const size_t OFF_RTOT    = 577888;    // u32[256]
static const size_t OFF_SCALE0  = 578144;    // 320
static const size_t OFF_SHIFT0  = 578464;    // 320
static const size_t OFF_BP      = 578784;    // 128
static const size_t OFF_SCALE1  = 578912;    // 128
static const size_t OFF_SHIFT1  = 579040;    // 128
static const size_t OFF_WVEC    = 579168;    // 128
static const size_t OFF_WPT     = 579296;    // 100*200
static const size_t OFF_WRELT   = 599296;    // 100*100
static const size_t OFF_V       = 609296;    // 237*100 (pitch 100 f32)
static const size_t OFF_PSI     = 633040;    // 256
static const size_t OFF_PHI0    = 633296;    // 100000
static const size_t OFF_PHI1    = 733296;    // 100000
static const size_t OFF_RELE64  = 833296;    // u64[500000] (even -> 8B aligned)
static const size_t OFF_INC     = 1833296;   // u32[1000000]
static const size_t OFF_UE      = 2833296;   // u16[100000*256] = 12.8M floats
static const size_t TOTAL_F     = 15633296;  // ~62.5 MB

__device__ __forceinline__ float bf2f(u16 u){ return __uint_as_float(((u32)u)<<16); }
__device__ __forceinline__ u16 f2bf(float f){
  u32 x = __float_as_uint(f);
  x += 0x7FFFu + ((x>>16)&1u);
  return (u16)(x>>16);
}
__device__ __forceinline__ void ld4a(const u16* p, float* o){
  ushort4 u = *(const ushort4*)p;
  o[0]=bf2f(u.x); o[1]=bf2f(u.y); o[2]=bf2f(u.z); o[3]=bf2f(u.w);
}
__device__ __forceinline__ void ld4f(const float* p, float* o){
  float4 v = *(const float4*)p;
  o[0]=v.x; o[1]=v.y; o[2]=v.z; o[3]=v.w;
}
__device__ __forceinline__ float eluf(float v){ return v>0.f ? v : expf(v)-1.f; }
__device__ __forceinline__ float ewt(float t){ return expf( t>0.f ? -t : -0.01f*t ); }

// ---- pass A: deg atomics (spread) + per-block rel histogram in LDS ----
__global__ __launch_bounds__(256) void k_histA(const int* __restrict__ trip,
                                               u32* __restrict__ deg, u32* __restrict__ bhist){
  __shared__ u32 lh[256];
  int t = threadIdx.x, b = blockIdx.x;
  lh[t] = 0u;
  __syncthreads();
  int e0 = b*CHUNK, e1 = e0+CHUNK; if (e1 > E_EDGES) e1 = E_EDGES;
  for (int e=e0+t; e<e1; e+=256){
    int3 tr = ((const int3*)trip)[e];
    atomicAdd(&deg[tr.x], 1u);
    atomicAdd(&deg[tr.y], 1u);
    atomicAdd(&lh[tr.z], 1u);
  }
  __syncthreads();
  bhist[b*256 + t] = lh[t];
}

// ---- hierarchical scan, stage A: per-chunk deg sums ----
__global__ __launch_bounds__(256) void k_scanA(const u32* __restrict__ deg, u32* __restrict__ part){
  __shared__ u32 red[256];
  int b = blockIdx.x, t = threadIdx.x;
  int c0 = b*ECHUNK, c1 = c0+ECHUNK; if (c1 > NENT) c1 = NENT; if (c0 > NENT) c0 = NENT;
  u32 s=0;
  for (int n=c0+t; n<c1; n+=256) s += deg[n];
  red[t]=s; __syncthreads();
  for (int m=128;m>=1;m>>=1){ if (t<m) red[t]+=red[t+m]; __syncthreads(); }
  if (t==0) part[b]=red[0];
}

// ---- stage R: per-rel scan of bhist columns ----
__global__ __launch_bounds__(256) void k_scanR(const u32* __restrict__ bhist,
                                               u32* __restrict__ rbase, u32* __restrict__ rtot){
  __shared__ u32 sd[256];
  int r = blockIdx.x, t = threadIdx.x;
  u32 v0 = bhist[(size_t)(2*t)*256 + r];
  u32 v1 = bhist[(size_t)(2*t+1)*256 + r];
  u32 v = v0+v1;
  sd[t]=v; __syncthreads();
  for (int o=1;o<256;o<<=1){ u32 x=(t>=o)?sd[t-o]:0u; __syncthreads(); sd[t]+=x; __syncthreads(); }
  u32 ex = sd[t]-v;
  rbase[(size_t)r*NB + 2*t]   = ex;
  rbase[(size_t)r*NB + 2*t+1] = ex+v0;
  if (t==255) rtot[r] = sd[255];
}

// ---- stage B: scan part[256] -> base; scan rtot -> roff/relcntf ----
__global__ __launch_bounds__(256) void k_scanB(const u32* __restrict__ part, u32* __restrict__ base,
                                               u32* __restrict__ offs,
                                               const u32* __restrict__ rtot, u32* __restrict__ roff,
                                               float* __restrict__ relcntf){
  __shared__ u32 sd[256];
  int t = threadIdx.x;
  u32 v = part[t];
  sd[t]=v; __syncthreads();
  for (int o=1;o<256;o<<=1){ u32 x=(t>=o)?sd[t-o]:0u; __syncthreads(); sd[t]+=x; __syncthreads(); }
  base[t] = sd[t]-v;
  if (t==255) offs[NENT] = sd[255];
  __syncthreads();
  u32 rv = (t<NREL)? rtot[t] : 0u;
  sd[t]=rv; __syncthreads();
  for (int o=1;o<256;o<<=1){ u32 x=(t>=o)?sd[t-o]:0u; __syncthreads(); sd[t]+=x; __syncthreads(); }
  if (t<NREL){ roff[t]=sd[t]-rv; relcntf[t]=(float)rv; }
  if (t==NREL-1) roff[NREL]=sd[t];
}

// ---- stage C: per-chunk exclusive scan -> offs ----
__global__ __launch_bounds__(256) void k_scanC(const u32* __restrict__ deg, const u32* __restrict__ base,
                                               u32* __restrict__ offs){
  __shared__ u32 sd[256];
  int b = blockIdx.x, t = threadIdx.x;
  int c0 = b*ECHUNK;
  int cend = c0+ECHUNK; if (cend > NENT) cend = NENT;
  int n0 = c0 + 2*t;
  u32 d0 = (n0   < cend)? deg[n0]   : 0u;
  u32 d1 = (n0+1 < cend)? deg[n0+1] : 0u;
  u32 v = d0+d1;
  sd[t]=v; __syncthreads();
  for (int o=1;o<256;o<<=1){ u32 x=(t>=o)?sd[t-o]:0u; __syncthreads(); sd[t]+=x; __syncthreads(); }
  u32 ex = base[b] + sd[t]-v;
  if (n0   < cend) offs[n0]   = ex;
  if (n0+1 < cend) offs[n0+1] = ex+d0;
}

// ---- pass B: fill incidence lists (rel part atomic-free, packed endpoints) ----
__global__ __launch_bounds__(256) void k_incB(const int* __restrict__ trip,
                      const u32* __restrict__ offs, u32* __restrict__ cur,
                      const u32* __restrict__ roff, const u32* __restrict__ rbase,
                      u32* __restrict__ inc, u64* __restrict__ rele64){
  __shared__ u32 lh[256];
  int t = threadIdx.x, b = blockIdx.x;
  lh[t] = 0u;
  __syncthreads();
  int e0 = b*CHUNK, e1 = e0+CHUNK; if (e1 > E_EDGES) e1 = E_EDGES;
  for (int e=e0+t; e<e1; e+=256){
    int3 tr = ((const int3*)trip)[e];
    u32 p0 = offs[tr.x] + atomicAdd(&cur[tr.x], 1u);
    inc[p0] = (u32)tr.y | ((u32)tr.z<<17);
    u32 p1 = offs[tr.y] + atomicAdd(&cur[tr.y], 1u);
    inc[p1] = (u32)tr.x | ((u32)tr.z<<17) | (1u<<25);
    u32 loff = atomicAdd(&lh[tr.z], 1u);
    rele64[roff[tr.z] + rbase[(u32)tr.z*NB + b] + loff] = (u64)(u32)tr.x | ((u64)(u32)tr.y<<17);
  }
}

// ---- bn0 entity-column stats: slot-parallel, 2-row unrolled ----
__global__ __launch_bounds__(256) void k_entstats(const float* __restrict__ ent, const u32* __restrict__ deg,
                                                  float* __restrict__ S1, float* __restrict__ S2){
  __shared__ float s1B[DIM], s2B[DIM];
  for (int i=threadIdx.x;i<DIM;i+=256){ s1B[i]=0.f; s2B[i]=0.f; }
  __syncthreads();
  int lane = threadIdx.x & 31;
  int slot = (blockIdx.x*256 + threadIdx.x) >> 5;
  int nslots = gridDim.x*8;
  bool act = lane < 25;
  int dbase = lane*4;
  float s1[4]={0,0,0,0}, s2[4]={0,0,0,0};
  int n = slot;
  for (; n + nslots < NENT; n += 2*nslots){
    float wa = (float)deg[n];
    float wb = (float)deg[n+nslots];
    if (act){
      float xa[4], xb[4];
      ld4f(ent + (size_t)n*DIM + dbase, xa);
      ld4f(ent + (size_t)(n+nslots)*DIM + dbase, xb);
      #pragma unroll
      for (int j=0;j<4;j++){
        s1[j] += wa*xa[j] + wb*xb[j];
        s2[j] += wa*xa[j]*xa[j] + wb*xb[j]*xb[j];
      }
    }
  }
  for (; n < NENT; n += nslots){
    float w = (float)deg[n];
    if (act){
      float x[4];
      ld4f(ent + (size_t)n*DIM + dbase, x);
      #pragma unroll
      for (int j=0;j<4;j++){ s1[j] += w*x[j]; s2[j] += w*x[j]*x[j]; }
    }
  }
  if (act){
    #pragma unroll
    for (int j=0;j<4;j++){ atomicAdd(&s1B[dbase+j], s1[j]); atomicAdd(&s2B[dbase+j], s2[j]); }
  }
  __syncthreads();
  for (int i=threadIdx.x;i<DIM;i+=256){ atomicAdd(&S1[i], s1B[i]); atomicAdd(&S2[i], s2B[i]); }
}

__global__ void k_relstats(const float* __restrict__ rel, const float* __restrict__ relcnt, float* __restrict__ S2r){
  int d = threadIdx.x;
  if (d >= DIM) return;
  float s=0.f;
  for (int r=0;r<NREL;r++){
    float x = rel[r*DIM+d];
    s += relcnt[r]*x*x;
  }
  S2r[d] = s;
}

__global__ void k_scale0(const float* __restrict__ g0, const float* __restrict__ b0,
                         const float* __restrict__ S1, const float* __restrict__ S2, const float* __restrict__ S2r,
                         float* __restrict__ scale0, float* __restrict__ shift0){
  int j = threadIdx.x;            // 320
  if (j >= TDIM) return;
  float mean, var;
  if (j < 200){
    int d = (j<100)? j : j-100;
    mean = S1[d] * (1.0f/TWO_E);
    var  = S2[d] * (1.0f/TWO_E) - mean*mean;
  } else {
    mean = 0.0f;
    var  = S2r[j-200] * (1.0f/E_EDGES);
  }
  float sc = g0[j] * rsqrtf(var + BN_EPS);
  scale0[j] = sc;
  shift0[j] = b0[j] - mean*sc;
}

__global__ void k_foldW(const float* __restrict__ aW, const float* __restrict__ scale0,
                        float* __restrict__ Wpt, float* __restrict__ Wrelt){
  int idx = blockIdx.x*256 + threadIdx.x;
  if (idx < 20000){
    int d = idx/200, kk = idx%200;
    int k = (kk<100)? kk : kk-100;
    int j = (kk<100)? d : 100+d;
    Wpt[idx] = aW[k*TDIM + j] * scale0[j];
  } else if (idx < 30000){
    int i2 = idx - 20000;
    int d = i2/100, k = i2%100;
    Wrelt[i2] = aW[k*TDIM + 200 + d] * scale0[200+d];
  }
}

__global__ void k_bp(const float* __restrict__ aW, const float* __restrict__ ab,
                     const float* __restrict__ shift0, float* __restrict__ bp){
  int k = blockIdx.x;
  int l = threadIdx.x;            // 64
  float s=0.f;
  for (int j=l;j<TDIM;j+=64) s += aW[k*TDIM+j] * shift0[j];
  #pragma unroll
  for (int m=32;m>=1;m>>=1) s += __shfl_xor(s, m, 64);
  if (l==0) bp[k] = s + ab[k];
}

__global__ void k_V(const float* __restrict__ rel, const float* __restrict__ Wrelt, float* __restrict__ V){
  __shared__ float rf[DIM];
  int r = blockIdx.x;
  int k = threadIdx.x;            // 128
  if (k < DIM) rf[k] = rel[r*DIM+k];
  __syncthreads();
  if (k >= DIM) return;
  float s=0.f;
  for (int d=0;d<DIM;d++) s += Wrelt[d*DIM+k]*rf[d];
  V[r*DIM+k] = s;
}

// ---- UEp[n][256] bf16: U0 at col 0..99, U1 at col 128..227 ----
// float4 LDS reads: rows are 144B (16B-aligned), 8 ds_read_b128 per d instead of 32 ds_read_b32
__global__ __launch_bounds__(256) void k_U(const float* __restrict__ ent, const float* __restrict__ Wpt,
                                           u16* __restrict__ UEp){
  __shared__ float sh[DIM][36];
  int n0 = blockIdx.x*32;         // 3125*32 = 100000
  for (int idx=threadIdx.x; idx<32*DIM; idx+=256){
    int n = idx/DIM, d = idx%DIM;
    sh[d][n] = ent[(size_t)(n0+n)*DIM + d];
  }
  __syncthreads();
  int kk = threadIdx.x;
  if (kk >= 200) return;
  float acc[32];
  #pragma unroll
  for (int i=0;i<32;i++) acc[i]=0.f;
  for (int d=0;d<DIM;d++){
    float w = Wpt[d*200+kk];
    #pragma unroll
    for (int ib=0;ib<8;ib++){
      float4 s4 = *(const float4*)&sh[d][ib*4];
      acc[ib*4+0] += w*s4.x;
      acc[ib*4+1] += w*s4.y;
      acc[ib*4+2] += w*s4.z;
      acc[ib*4+3] += w*s4.w;
    }
  }
  int col = (kk<100)? kk : (28+kk);   // 128 + (kk-100)
  for (int i=0;i<32;i++) UEp[(size_t)(n0+i)*PITCH + col] = f2bf(acc[i]);
}

// ---- bn1 stats over 2E rows of c_pre (edge sweep, 2-edge unrolled) ----
__global__ __launch_bounds__(256) void k_cstats(const int* __restrict__ trip,
    const u16* __restrict__ UEp, const float* __restrict__ V, const float* __restrict__ bp,
    float* __restrict__ Sc, float* __restrict__ Sc2){
  __shared__ float scB[DIM], sc2B[DIM];
  for (int i=threadIdx.x;i<DIM;i+=256){ scB[i]=0.f; sc2B[i]=0.f; }
  __syncthreads();
  int lane = threadIdx.x & 31;
  int slot = (blockIdx.x*256 + threadIdx.x) >> 5;
  int nslots = gridDim.x*8;
  bool act = lane < 25;
  int dbase = lane*4;
  float bpv[4]={0,0,0,0};
  if (act) ld4f(bp+dbase, bpv);
  float sc[4]={0,0,0,0}, sc2[4]={0,0,0,0};
  int e = slot;
  for (; e + nslots < E_EDGES; e += 2*nslots){
    int3 ta = ((const int3*)trip)[e];
    int3 tb = ((const int3*)trip)[e+nslots];
    if (act){
      const u16* rxa = UEp + (size_t)ta.x*PITCH;
      const u16* rya = UEp + (size_t)ta.y*PITCH;
      const u16* rxb = UEp + (size_t)tb.x*PITCH;
      const u16* ryb = UEp + (size_t)tb.y*PITCH;
      float Pa[4],Qa[4],Ra[4],Sa[4],Va[4];
      float Pb[4],Qb[4],Rb[4],Sb[4],Vb[4];
      ld4a(rxa+dbase, Pa);      ld4a(rya+128+dbase, Qa);
      ld4a(rya+dbase, Ra);      ld4a(rxa+128+dbase, Sa);
      ld4a(rxb+dbase, Pb);      ld4a(ryb+128+dbase, Qb);
      ld4a(ryb+dbase, Rb);      ld4a(rxb+128+dbase, Sb);
      ld4f(V+(size_t)ta.z*DIM+dbase, Va);
      ld4f(V+(size_t)tb.z*DIM+dbase, Vb);
      #pragma unroll
      for (int i=0;i<4;i++){
        float cfa = Pa[i]+Qa[i]+Va[i]+bpv[i];
        float cia = Ra[i]+Sa[i]-Va[i]+bpv[i];
        float cfb = Pb[i]+Qb[i]+Vb[i]+bpv[i];
        float cib = Rb[i]+Sb[i]-Vb[i]+bpv[i];
        sc[i]  += (cfa+cia) + (cfb+cib);
        sc2[i] += cfa*cfa + cia*cia + cfb*cfb + cib*cib;
      }
    }
  }
  for (; e < E_EDGES; e += nslots){
    int3 t = ((const int3*)trip)[e];
    if (act){
      const u16* rx = UEp + (size_t)t.x*PITCH;
      const u16* ry = UEp + (size_t)t.y*PITCH;
      float P[4],Q[4],R[4],S[4],Vv[4];
      ld4a(rx+dbase, P);
      ld4a(ry+128+dbase, Q);
      ld4a(ry+dbase, R);
      ld4a(rx+128+dbase, S);
      ld4f(V+(size_t)t.z*DIM+dbase, Vv);
      #pragma unroll
      for (int i=0;i<4;i++){
        float cf = P[i]+Q[i]+Vv[i]+bpv[i];
        float ci = R[i]+S[i]-Vv[i]+bpv[i];
        sc[i]  += cf+ci;
        sc2[i] += cf*cf + ci*ci;
      }
    }
  }
  if (act){
    #pragma unroll
    for (int i=0;i<4;i++){ atomicAdd(&scB[dbase+i], sc[i]); atomicAdd(&sc2B[dbase+i], sc2[i]); }
  }
  __syncthreads();
  for (int i=threadIdx.x;i<DIM;i+=256){ atomicAdd(&Sc[i], scB[i]); atomicAdd(&Sc2[i], sc2B[i]); }
}

// ---- bn1 affine + attention vector w + scalar C ----
__global__ void k_bn1x(const float* __restrict__ g1, const float* __restrict__ b1,
                       const float* __restrict__ Sc, const float* __restrict__ Sc2,
                       const float* __restrict__ bp, const float* __restrict__ a2W, const float* __restrict__ a2b,
                       float* __restrict__ scale1, float* __restrict__ shift1,
                       float* __restrict__ wvec, float* __restrict__ consts){
  __shared__ float red[128];
  int k = threadIdx.x;            // 128
  float contrib = 0.f;
  if (k < DIM){
    float mean = Sc[k]*(1.0f/TWO_E);
    float var  = Sc2[k]*(1.0f/TWO_E) - mean*mean;
    float s = g1[k] * rsqrtf(var + BN_EPS);
    float sh = b1[k] - mean*s;
    float a2 = a2W[k];
    scale1[k] = s;
    shift1[k] = sh;
    float wv = s*a2;
    wvec[k] = wv;
    contrib = bp[k]*wv + sh*a2;
  }
  red[k] = contrib;
  __syncthreads();
  for (int m=64;m>=1;m>>=1){ if (k<m) red[k]+=red[k+m]; __syncthreads(); }
  if (k==0) consts[0] = red[0] + a2b[0];
}

// ---- phi0[n]=U0[n].w, phi1[n]=U1[n].w ----
__global__ __launch_bounds__(256) void k_phi(const u16* __restrict__ UEp, const float* __restrict__ wvec,
                                             float* __restrict__ phi0, float* __restrict__ phi1){
  int lane = threadIdx.x & 31;
  int n = blockIdx.x*8 + (threadIdx.x>>5);
  bool act = lane < 25;
  int dbase = lane*4;
  float w4[4]={0,0,0,0};
  float p0=0.f, p1=0.f;
  if (act){
    ld4f(wvec+dbase, w4);
    float P[4], Q[4];
    ld4a(UEp + (size_t)n*PITCH + dbase, P);
    ld4a(UEp + (size_t)n*PITCH + 128 + dbase, Q);
    #pragma unroll
    for (int i=0;i<4;i++){ p0 += P[i]*w4[i]; p1 += Q[i]*w4[i]; }
  }
  #pragma unroll
  for (int m=16;m>=1;m>>=1){ p0 += __shfl_xor(p0,m,32); p1 += __shfl_xor(p1,m,32); }
  if (lane==0){ phi0[n]=p0; phi1[n]=p1; }
}

// ---- psi[r]=V[r].w ----
__global__ void k_psi(const float* __restrict__ V, const float* __restrict__ wvec, float* __restrict__ psi){
  __shared__ float w[DIM];
  int t = threadIdx.x;            // 256
  if (t < DIM) w[t] = wvec[t];
  __syncthreads();
  if (t >= NREL) return;
  float s=0.f;
  for (int k=0;k<DIM;k++) s += V[t*DIM+k]*w[k];
  psi[t] = s;
}

// ---- entity aggregation: one 32-lane slot per entity, 2-edge unrolled ----
__global__ __launch_bounds__(256) void k_aggr_ent(const u32* __restrict__ offs, const u32* __restrict__ inc,
    const u16* __restrict__ UEp, const float* __restrict__ V,
    const float* __restrict__ phi0, const float* __restrict__ phi1, const float* __restrict__ psi,
    const float* __restrict__ consts, const float* __restrict__ bp,
    const float* __restrict__ scale1, const float* __restrict__ shift1,
    float* __restrict__ out){
  int lane = threadIdx.x & 31;
  int n = blockIdx.x*8 + (threadIdx.x>>5);
  bool act = lane < 25;
  int dbase = lane*4;
  u32 o0 = offs[n], o1 = offs[n+1];
  float C = consts[0];
  float p0n = phi0[n];
  float acc[4]={0,0,0,0};
  float wsum=0.f;
  u32 i = o0;
  for (; i+2 <= o1; i += 2){
    u32 pk0 = inc[i], pk1 = inc[i+1];
    u32 oth0 = pk0 & 0x1FFFFu,      oth1 = pk1 & 0x1FFFFu;
    u32 rr0  = (pk0>>17) & 0xFFu,   rr1  = (pk1>>17) & 0xFFu;
    float sg0 = (pk0>>25)? -1.f:1.f, sg1 = (pk1>>25)? -1.f:1.f;
    float ph0 = phi1[oth0], ph1 = phi1[oth1];
    float ps0 = psi[rr0],   ps1 = psi[rr1];
    float B0[4],V0[4],B1[4],V1[4];
    if (act){
      ld4a(UEp + (size_t)oth0*PITCH + 128 + dbase, B0);
      ld4a(UEp + (size_t)oth1*PITCH + 128 + dbase, B1);
      ld4f(V + (size_t)rr0*DIM + dbase, V0);
      ld4f(V + (size_t)rr1*DIM + dbase, V1);
    }
    float t0 = p0n + ph0 + sg0*ps0 + C;
    float t1 = p0n + ph1 + sg1*ps1 + C;
    float w0 = ewt(t0), w1 = ewt(t1);
    wsum += w0+w1;
    if (act){
      #pragma unroll
      for (int j=0;j<4;j++) acc[j] += w0*(B0[j]+sg0*V0[j]) + w1*(B1[j]+sg1*V1[j]);
    }
  }
  if (i < o1){
    u32 pk = inc[i];
    u32 oth = pk & 0x1FFFFu;
    u32 rr = (pk>>17) & 0xFFu;
    float sg = (pk>>25)? -1.f:1.f;
    float t = p0n + phi1[oth] + sg*psi[rr] + C;
    float w = ewt(t);
    wsum += w;
    if (act){
      float B[4], Vv[4];
      ld4a(UEp + (size_t)oth*PITCH + 128 + dbase, B);
      ld4f(V + (size_t)rr*DIM + dbase, Vv);
      #pragma unroll
      for (int j=0;j<4;j++) acc[j] += w*(B[j]+sg*Vv[j]);
    }
  }
  if (act){
    float o4[4];
    if (o1 == o0){
      o4[0]=o4[1]=o4[2]=o4[3]=0.f;
    } else {
      float P[4], bp4[4], s14[4], sh4[4];
      ld4a(UEp + (size_t)n*PITCH + dbase, P);
      ld4f(bp+dbase, bp4);
      ld4f(scale1+dbase, s14);
      ld4f(shift1+dbase, sh4);
      float inv = __frcp_rn(wsum);
      #pragma unroll
      for (int j=0;j<4;j++){
        float v = (P[j]+bp4[j])*s14[j] + sh4[j] + s14[j]*acc[j]*inv;
        o4[j] = eluf(v);
      }
    }
    *(float4*)(out + (size_t)n*DIM + dbase) = make_float4(o4[0],o4[1],o4[2],o4[3]);
  }
}

// ---- rel aggregation: NREL*RSEG blocks, 2-edge unrolled, LDS reduce + atomic burst ----
__global__ __launch_bounds__(256) void k_aggr_relP(
    const u32* __restrict__ roff, const u64* __restrict__ rele64,
    const u16* __restrict__ UEp, const float* __restrict__ V,
    const float* __restrict__ phi0, const float* __restrict__ phi1, const float* __restrict__ psi,
    const float* __restrict__ consts, const float* __restrict__ bp,
    const float* __restrict__ scale1, const float* __restrict__ shift1,
    float* __restrict__ relacc){
  __shared__ float red[8][104];
  int r   = blockIdx.x / RSEG;
  int seg = blockIdx.x % RSEG;
  int lane = threadIdx.x & 31;
  int slot = threadIdx.x >> 5;    // 8 slots
  bool act = lane < 25;
  int dbase = lane*4;
  float C = consts[0];
  float psir = psi[r];
  float bp4[4]={0,0,0,0}, s14[4]={0,0,0,0}, sh4[4]={0,0,0,0}, Vv[4]={0,0,0,0};
  if (act){
    ld4f(bp+dbase, bp4);
    ld4f(scale1+dbase, s14);
    ld4f(shift1+dbase, sh4);
    ld4f(V + (size_t)r*DIM + dbase, Vv);
  }
  u32 q0 = roff[r], q1 = roff[r+1];
  float acc[4]={0,0,0,0};
  for (u32 q = q0 + (u32)(seg*8+slot)*2; q < q1; q += (u32)(RSEG*8*2)){
    u64 pk0 = rele64[q];
    bool has1 = (q+1 < q1);
    u64 pk1 = has1 ? rele64[q+1] : pk0;
    u32 a0 = (u32)(pk0 & 0x1FFFFu), b0 = (u32)((pk0>>17) & 0x1FFFFu);
    u32 a1 = (u32)(pk1 & 0x1FFFFu), b1 = (u32)((pk1>>17) & 0x1FFFFu);
    float P0[4],Q0[4],R0[4],S0[4],P1[4],Q1[4],R1[4],S1[4];
    if (act){
      const u16* rx0 = UEp + (size_t)a0*PITCH;
      const u16* ry0 = UEp + (size_t)b0*PITCH;
      const u16* rx1 = UEp + (size_t)a1*PITCH;
      const u16* ry1 = UEp + (size_t)b1*PITCH;
      ld4a(rx0+dbase, P0);      ld4a(ry0+128+dbase, Q0);
      ld4a(ry0+dbase, R0);      ld4a(rx0+128+dbase, S0);
      ld4a(rx1+dbase, P1);      ld4a(ry1+128+dbase, Q1);
      ld4a(ry1+dbase, R1);      ld4a(rx1+128+dbase, S1);
    }
    float tf0 = phi0[a0] + phi1[b0] + psir + C;
    float ti0 = phi0[b0] + phi1[a0] - psir + C;
    float tf1 = phi0[a1] + phi1[b1] + psir + C;
    float ti1 = phi0[b1] + phi1[a1] - psir + C;
    float m1 = has1 ? 1.f : 0.f;
    float ef0 = ewt(tf0), ei0 = ewt(ti0);
    float ef1 = m1*ewt(tf1), ei1 = m1*ewt(ti1);
    if (act){
      #pragma unroll
      for (int j=0;j<4;j++){
        float cf0 = (P0[j]+Q0[j]+Vv[j]+bp4[j])*s14[j] + sh4[j];
        float ci0 = (R0[j]+S0[j]-Vv[j]+bp4[j])*s14[j] + sh4[j];
        float cf1 = (P1[j]+Q1[j]+Vv[j]+bp4[j])*s14[j] + sh4[j];
        float ci1 = (R1[j]+S1[j]-Vv[j]+bp4[j])*s14[j] + sh4[j];
        acc[j] += ef0*cf0 - ei0*ci0 + ef1*cf1 - ei1*ci1;
      }
    }
  }
  if (act){
    #pragma unroll
    for (int j=0;j<4;j++) red[slot][dbase+j] = acc[j];
  }
  __syncthreads();
  int k = threadIdx.x;
  if (k < DIM){
    float s = 0.f;
    #pragma unroll
    for (int sl=0;sl<8;sl++) s += red[sl][k];
    atomicAdd(&relacc[(size_t)r*DIM + k], s);
  }
}

// ---- finalize h_rel ----
__global__ void k_out_rel(const float* __restrict__ relacc, const float* __restrict__ relcnt,
                          float* __restrict__ out){
  int idx = blockIdx.x*256 + threadIdx.x;
  if (idx >= NREL*DIM) return;
  int r = idx/DIM;
  float cn = relcnt[r]; if (cn < 1.f) cn = 1.f;
  out[(size_t)NENT*DIM + idx] = eluf(relacc[idx]/cn);
}

extern "C" void kernel_launch(void* const* d_in, const int* in_sizes, int n_in,
                              void* d_out, int out_size, void* d_ws, size_t ws_size,
                              hipStream_t stream){
  const int*   trip = (const int*)d_in[0];
  const float* ent  = (const float*)d_in[1];
  const float* rel  = (const float*)d_in[2];
  const float* aW   = (const float*)d_in[3];
  const float* ab   = (const float*)d_in[4];
  const float* a2W  = (const float*)d_in[5];
  const float* a2b  = (const float*)d_in[6];
  const float* g0   = (const float*)d_in[7];
  const float* b0   = (const float*)d_in[8];
  const float* g1   = (const float*)d_in[9];
  const float* b1   = (const float*)d_in[10];
  float* out = (float*)d_out;
  float* wsf = (float*)d_ws;
  if (ws_size < TOTAL_F*sizeof(float)) return;
  u16* UEp  = (u16*)(wsf + OFF_UE);
  u32* deg  = (u32*)(wsf + OFF_DEG);
  u32* cur  = (u32*)(wsf + OFF_CUR);
  u32* offs = (u32*)(wsf + OFF_OFFS);
  u32* roff = (u32*)(wsf + OFF_ROFF);
  u32* bhist= (u32*)(wsf + OFF_BHIST);
  u32* rbase= (u32*)(wsf + OFF_RBASE);
  u32* part = (u32*)(wsf + OFF_PART);
  u32* base = (u32*)(wsf + OFF_BASE);
  u32* rtot = (u32*)(wsf + OFF_RTOT);
  u32* inc  = (u32*)(wsf + OFF_INC);
  u64* rele = (u64*)(wsf + OFF_RELE64);

  hipMemsetAsync(d_ws, 0, ZERO_END*sizeof(float), stream);

  k_histA<<<dim3(NB), dim3(256), 0, stream>>>(trip, deg, bhist);
  k_entstats<<<dim3(1024), dim3(256), 0, stream>>>(ent, deg, wsf+OFF_S1, wsf+OFF_S2);
  k_scanA<<<dim3(256), dim3(256), 0, stream>>>(deg, part);
  k_scanR<<<dim3(NREL), dim3(256), 0, stream>>>(bhist, rbase, rtot);
  k_scanB<<<dim3(1), dim3(256), 0, stream>>>(part, base, offs, rtot, roff, wsf+OFF_RELCNTF);
  k_scanC<<<dim3(256), dim3(256), 0, stream>>>(deg, base, offs);
  k_relstats<<<dim3(1), dim3(128), 0, stream>>>(rel, wsf+OFF_RELCNTF, wsf+OFF_S2R);
  k_scale0<<<dim3(1), dim3(320), 0, stream>>>(g0, b0, wsf+OFF_S1, wsf+OFF_S2, wsf+OFF_S2R,
                                              wsf+OFF_SCALE0, wsf+OFF_SHIFT0);
  k_foldW<<<dim3(118), dim3(256), 0, stream>>>(aW, wsf+OFF_SCALE0, wsf+OFF_WPT, wsf+OFF_WRELT);
  k_bp<<<dim3(100), dim3(64), 0, stream>>>(aW, ab, wsf+OFF_SHIFT0, wsf+OFF_BP);
  k_V<<<dim3(NREL), dim3(128), 0, stream>>>(rel, wsf+OFF_WRELT, wsf+OFF_V);
  k_U<<<dim3(NENT/32), dim3(256), 0, stream>>>(ent, wsf+OFF_WPT, UEp);
  k_incB<<<dim3(NB), dim3(256), 0, stream>>>(trip, offs, cur, roff, rbase, inc, rele);
  k_cstats<<<dim3(2048), dim3(256), 0, stream>>>(trip, UEp, wsf+OFF_V, wsf+OFF_BP,
                                                 wsf+OFF_SC, wsf+OFF_SC2);
  k_bn1x<<<dim3(1), dim3(128), 0, stream>>>(g1, b1, wsf+OFF_SC, wsf+OFF_SC2, wsf+OFF_BP, a2W, a2b,
                                            wsf+OFF_SCALE1, wsf+OFF_SHIFT1, wsf+OFF_WVEC, wsf+OFF_CONST);
  k_phi<<<dim3(NENT/8), dim3(256), 0, stream>>>(UEp, wsf+OFF_WVEC, wsf+OFF_PHI0, wsf+OFF_PHI1);
  k_psi<<<dim3(1), dim3(256), 0, stream>>>(wsf+OFF_V, wsf+OFF_WVEC, wsf+OFF_PSI);
  k_aggr_ent<<<dim3(NENT/8), dim3(256), 0, stream>>>(offs, inc, UEp, wsf+OFF_V,
                                                     wsf+OFF_PHI0, wsf+OFF_PHI1, wsf+OFF_PSI,
                                                     wsf+OFF_CONST, wsf+OFF_BP,
                                                     wsf+OFF_SCALE1, wsf+OFF_SHIFT1, out);
  k_aggr_relP<<<dim3(NREL*RSEG), dim3(256), 0, stream>>>(roff, rele, UEp, wsf+OFF_V,
                                                   wsf+OFF_PHI0, wsf+OFF_PHI1, wsf+OFF_PSI,
                                                   wsf+OFF_CONST, wsf+OFF_BP,
                                                   wsf+OFF_SCALE1, wsf+OFF_SHIFT1,
                                                   wsf+OFF_RELACC);
  k_out_rel<<<dim3((NREL*DIM+255)/256), dim3(256), 0, stream>>>(wsf+OFF_RELACC, wsf+OFF_RELCNTF, out);
}

// Round 14
// 538.047 us; speedup vs baseline: 1.0284x; 1.0284x over previous
//
#include <hip/hip_runtime.h>
#include <hip/hip_bf16.h>

#define E_EDGES 500000
#define NENT    100000
#define NREL    237
#define DIM     100
#define TDIM    300
#define TWO_E   1000000
#define BN_EPS  1e-5f
#define PITCH   256        // u16 elems per UEp row (512B): U0 at +0, U1 at +128
#define NB      512        // histogram/scatter blocks
#define CHUNK   977        // ceil(E_EDGES/NB)
#define RSEG    16         // segments per rel in rel-aggregation
#define ECHUNK  391        // entities per scan chunk (256*391 >= NENT)

typedef unsigned short u16;
typedef unsigned int   u32;
typedef unsigned long long u64;

// ---------- ws layout (offsets in floats) ----------
static const size_t OFF_DEG     = 0;         // u32[100000] (zeroed)
static const size_t OFF_CUR     = 100000;    // u32[100000] (zeroed)
static const size_t OFF_S1      = 200000;    // 128 (zeroed)
static const size_t OFF_S2      = 200128;    // 128 (zeroed)
static const size_t OFF_S2R     = 200256;    // 128 (zeroed)
static const size_t OFF_SC      = 200384;    // 128 (zeroed)
static const size_t OFF_SC2     = 200512;    // 128 (zeroed)
static const size_t OFF_CONST   = 200640;    // 64  (zeroed)
static const size_t OFF_RELACC  = 200704;    // 23744 (zeroed)
static const size_t ZERO_END    = 224448;
static const size_t OFF_OFFS    = 224448;    // u32[100001]
static const size_t OFF_ROFF    = 324464;    // u32[240]
static const size_t OFF_RELCNTF = 324704;    // float[256]
static const size_t OFF_BHIST   = 324960;    // u32[NB*256]
static const size_t OFF_RBASE   = 456032;    // u32[237*NB]
static const size_t OFF_PART    = 577376;    // u32[256]
static const size_t OFF_BASE    = 577632;    // u32[256]
static const size_t OFF_RTOT    = 577888;    // u32[256]
static const size_t OFF_SCALE0  = 578144;    // 320
static const size_t OFF_SHIFT0  = 578464;    // 320
static const size_t OFF_BP      = 578784;    // 128
static const size_t OFF_SCALE1  = 578912;    // 128
static const size_t OFF_SHIFT1  = 579040;    // 128
static const size_t OFF_WVEC    = 579168;    // 128
static const size_t OFF_WPT     = 579296;    // 100*200
static const size_t OFF_WRELT   = 599296;    // 100*100
static const size_t OFF_V       = 609296;    // 237*100 (pitch 100 f32)
static const size_t OFF_PSI     = 633040;    // 256
static const size_t OFF_PHI0    = 633296;    // 100000
static const size_t OFF_PHI1    = 733296;    // 100000
static const size_t OFF_RELE64  = 833296;    // u64[500000] (even -> 8B aligned)
static const size_t OFF_INC     = 1833296;   // u32[1000000]
static const size_t OFF_UE      = 2833296;   // u16[100000*256] = 12.8M floats
static const size_t TOTAL_F     = 15633296;  // ~62.5 MB

__device__ __forceinline__ float bf2f(u16 u){ return __uint_as_float(((u32)u)<<16); }
__device__ __forceinline__ u16 f2bf(float f){
  u32 x = __float_as_uint(f);
  x += 0x7FFFu + ((x>>16)&1u);
  return (u16)(x>>16);
}
__device__ __forceinline__ void ld4a(const u16* p, float* o){
  ushort4 u = *(const ushort4*)p;
  o[0]=bf2f(u.x); o[1]=bf2f(u.y); o[2]=bf2f(u.z); o[3]=bf2f(u.w);
}
__device__ __forceinline__ void ld4f(const float* p, float* o){
  float4 v = *(const float4*)p;
  o[0]=v.x; o[1]=v.y; o[2]=v.z; o[3]=v.w;
}
__device__ __forceinline__ float eluf(float v){ return v>0.f ? v : expf(v)-1.f; }
__device__ __forceinline__ float ewt(float t){ return expf( t>0.f ? -t : -0.01f*t ); }

// ---- pass A: deg atomics (spread) + per-block rel histogram in LDS ----
__global__ __launch_bounds__(256) void k_histA(const int* __restrict__ trip,
                                               u32* __restrict__ deg, u32* __restrict__ bhist){
  __shared__ u32 lh[256];
  int t = threadIdx.x, b = blockIdx.x;
  lh[t] = 0u;
  __syncthreads();
  int e0 = b*CHUNK, e1 = e0+CHUNK; if (e1 > E_EDGES) e1 = E_EDGES;
  for (int e=e0+t; e<e1; e+=256){
    int3 tr = ((const int3*)trip)[e];
    atomicAdd(&deg[tr.x], 1u);
    atomicAdd(&deg[tr.y], 1u);
    atomicAdd(&lh[tr.z], 1u);
  }
  __syncthreads();
  bhist[b*256 + t] = lh[t];
}

// ---- hierarchical scan, stage A: per-chunk deg sums ----
__global__ __launch_bounds__(256) void k_scanA(const u32* __restrict__ deg, u32* __restrict__ part){
  __shared__ u32 red[256];
  int b = blockIdx.x, t = threadIdx.x;
  int c0 = b*ECHUNK, c1 = c0+ECHUNK; if (c1 > NENT) c1 = NENT; if (c0 > NENT) c0 = NENT;
  u32 s=0;
  for (int n=c0+t; n<c1; n+=256) s += deg[n];
  red[t]=s; __syncthreads();
  for (int m=128;m>=1;m>>=1){ if (t<m) red[t]+=red[t+m]; __syncthreads(); }
  if (t==0) part[b]=red[0];
}

// ---- stage R: per-rel scan of bhist columns ----
__global__ __launch_bounds__(256) void k_scanR(const u32* __restrict__ bhist,
                                               u32* __restrict__ rbase, u32* __restrict__ rtot){
  __shared__ u32 sd[256];
  int r = blockIdx.x, t = threadIdx.x;
  u32 v0 = bhist[(size_t)(2*t)*256 + r];
  u32 v1 = bhist[(size_t)(2*t+1)*256 + r];
  u32 v = v0+v1;
  sd[t]=v; __syncthreads();
  for (int o=1;o<256;o<<=1){ u32 x=(t>=o)?sd[t-o]:0u; __syncthreads(); sd[t]+=x; __syncthreads(); }
  u32 ex = sd[t]-v;
  rbase[(size_t)r*NB + 2*t]   = ex;
  rbase[(size_t)r*NB + 2*t+1] = ex+v0;
  if (t==255) rtot[r] = sd[255];
}

// ---- stage B: scan part[256] -> base; scan rtot -> roff/relcntf ----
__global__ __launch_bounds__(256) void k_scanB(const u32* __restrict__ part, u32* __restrict__ base,
                                               u32* __restrict__ offs,
                                               const u32* __restrict__ rtot, u32* __restrict__ roff,
                                               float* __restrict__ relcntf){
  __shared__ u32 sd[256];
  int t = threadIdx.x;
  u32 v = part[t];
  sd[t]=v; __syncthreads();
  for (int o=1;o<256;o<<=1){ u32 x=(t>=o)?sd[t-o]:0u; __syncthreads(); sd[t]+=x; __syncthreads(); }
  base[t] = sd[t]-v;
  if (t==255) offs[NENT] = sd[255];
  __syncthreads();
  u32 rv = (t<NREL)? rtot[t] : 0u;
  sd[t]=rv; __syncthreads();
  for (int o=1;o<256;o<<=1){ u32 x=(t>=o)?sd[t-o]:0u; __syncthreads(); sd[t]+=x; __syncthreads(); }
  if (t<NREL){ roff[t]=sd[t]-rv; relcntf[t]=(float)rv; }
  if (t==NREL-1) roff[NREL]=sd[t];
}

// ---- stage C: per-chunk exclusive scan -> offs ----
__global__ __launch_bounds__(256) void k_scanC(const u32* __restrict__ deg, const u32* __restrict__ base,
                                               u32* __restrict__ offs){
  __shared__ u32 sd[256];
  int b = blockIdx.x, t = threadIdx.x;
  int c0 = b*ECHUNK;
  int cend = c0+ECHUNK; if (cend > NENT) cend = NENT;
  int n0 = c0 + 2*t;
  u32 d0 = (n0   < cend)? deg[n0]   : 0u;
  u32 d1 = (n0+1 < cend)? deg[n0+1] : 0u;
  u32 v = d0+d1;
  sd[t]=v; __syncthreads();
  for (int o=1;o<256;o<<=1){ u32 x=(t>=o)?sd[t-o]:0u; __syncthreads(); sd[t]+=x; __syncthreads(); }
  u32 ex = base[b] + sd[t]-v;
  if (n0   < cend) offs[n0]   = ex;
  if (n0+1 < cend) offs[n0+1] = ex+d0;
}

// ---- pass B: fill incidence lists (rel part atomic-free, packed endpoints) ----
__global__ __launch_bounds__(256) void k_incB(const int* __restrict__ trip,
                      const u32* __restrict__ offs, u32* __restrict__ cur,
                      const u32* __restrict__ roff, const u32* __restrict__ rbase,
                      u32* __restrict__ inc, u64* __restrict__ rele64){
  __shared__ u32 lh[256];
  int t = threadIdx.x, b = blockIdx.x;
  lh[t] = 0u;
  __syncthreads();
  int e0 = b*CHUNK, e1 = e0+CHUNK; if (e1 > E_EDGES) e1 = E_EDGES;
  for (int e=e0+t; e<e1; e+=256){
    int3 tr = ((const int3*)trip)[e];
    u32 p0 = offs[tr.x] + atomicAdd(&cur[tr.x], 1u);
    inc[p0] = (u32)tr.y | ((u32)tr.z<<17);
    u32 p1 = offs[tr.y] + atomicAdd(&cur[tr.y], 1u);
    inc[p1] = (u32)tr.x | ((u32)tr.z<<17) | (1u<<25);
    u32 loff = atomicAdd(&lh[tr.z], 1u);
    rele64[roff[tr.z] + rbase[(u32)tr.z*NB + b] + loff] = (u64)(u32)tr.x | ((u64)(u32)tr.y<<17);
  }
}

// ---- bn0 entity-column stats: slot-parallel, 2-row unrolled ----
__global__ __launch_bounds__(256) void k_entstats(const float* __restrict__ ent, const u32* __restrict__ deg,
                                                  float* __restrict__ S1, float* __restrict__ S2){
  __shared__ float s1B[DIM], s2B[DIM];
  for (int i=threadIdx.x;i<DIM;i+=256){ s1B[i]=0.f; s2B[i]=0.f; }
  __syncthreads();
  int lane = threadIdx.x & 31;
  int slot = (blockIdx.x*256 + threadIdx.x) >> 5;
  int nslots = gridDim.x*8;
  bool act = lane < 25;
  int dbase = lane*4;
  float s1[4]={0,0,0,0}, s2[4]={0,0,0,0};
  int n = slot;
  for (; n + nslots < NENT; n += 2*nslots){
    float wa = (float)deg[n];
    float wb = (float)deg[n+nslots];
    if (act){
      float xa[4], xb[4];
      ld4f(ent + (size_t)n*DIM + dbase, xa);
      ld4f(ent + (size_t)(n+nslots)*DIM + dbase, xb);
      #pragma unroll
      for (int j=0;j<4;j++){
        s1[j] += wa*xa[j] + wb*xb[j];
        s2[j] += wa*xa[j]*xa[j] + wb*xb[j]*xb[j];
      }
    }
  }
  for (; n < NENT; n += nslots){
    float w = (float)deg[n];
    if (act){
      float x[4];
      ld4f(ent + (size_t)n*DIM + dbase, x);
      #pragma unroll
      for (int j=0;j<4;j++){ s1[j] += w*x[j]; s2[j] += w*x[j]*x[j]; }
    }
  }
  if (act){
    #pragma unroll
    for (int j=0;j<4;j++){ atomicAdd(&s1B[dbase+j], s1[j]); atomicAdd(&s2B[dbase+j], s2[j]); }
  }
  __syncthreads();
  for (int i=threadIdx.x;i<DIM;i+=256){ atomicAdd(&S1[i], s1B[i]); atomicAdd(&S2[i], s2B[i]); }
}

__global__ void k_relstats(const float* __restrict__ rel, const float* __restrict__ relcnt, float* __restrict__ S2r){
  int d = threadIdx.x;
  if (d >= DIM) return;
  float s=0.f;
  for (int r=0;r<NREL;r++){
    float x = rel[r*DIM+d];
    s += relcnt[r]*x*x;
  }
  S2r[d] = s;
}

__global__ void k_scale0(const float* __restrict__ g0, const float* __restrict__ b0,
                         const float* __restrict__ S1, const float* __restrict__ S2, const float* __restrict__ S2r,
                         float* __restrict__ scale0, float* __restrict__ shift0){
  int j = threadIdx.x;            // 320
  if (j >= TDIM) return;
  float mean, var;
  if (j < 200){
    int d = (j<100)? j : j-100;
    mean = S1[d] * (1.0f/TWO_E);
    var  = S2[d] * (1.0f/TWO_E) - mean*mean;
  } else {
    mean = 0.0f;
    var  = S2r[j-200] * (1.0f/E_EDGES);
  }
  float sc = g0[j] * rsqrtf(var + BN_EPS);
  scale0[j] = sc;
  shift0[j] = b0[j] - mean*sc;
}

__global__ void k_foldW(const float* __restrict__ aW, const float* __restrict__ scale0,
                        float* __restrict__ Wpt, float* __restrict__ Wrelt){
  int idx = blockIdx.x*256 + threadIdx.x;
  if (idx < 20000){
    int d = idx/200, kk = idx%200;
    int k = (kk<100)? kk : kk-100;
    int j = (kk<100)? d : 100+d;
    Wpt[idx] = aW[k*TDIM + j] * scale0[j];
  } else if (idx < 30000){
    int i2 = idx - 20000;
    int d = i2/100, k = i2%100;
    Wrelt[i2] = aW[k*TDIM + 200 + d] * scale0[200+d];
  }
}

__global__ void k_bp(const float* __restrict__ aW, const float* __restrict__ ab,
                     const float* __restrict__ shift0, float* __restrict__ bp){
  int k = blockIdx.x;
  int l = threadIdx.x;            // 64
  float s=0.f;
  for (int j=l;j<TDIM;j+=64) s += aW[k*TDIM+j] * shift0[j];
  #pragma unroll
  for (int m=32;m>=1;m>>=1) s += __shfl_xor(s, m, 64);
  if (l==0) bp[k] = s + ab[k];
}

__global__ void k_V(const float* __restrict__ rel, const float* __restrict__ Wrelt, float* __restrict__ V){
  __shared__ float rf[DIM];
  int r = blockIdx.x;
  int k = threadIdx.x;            // 128
  if (k < DIM) rf[k] = rel[r*DIM+k];
  __syncthreads();
  if (k >= DIM) return;
  float s=0.f;
  for (int d=0;d<DIM;d++) s += Wrelt[d*DIM+k]*rf[d];
  V[r*DIM+k] = s;
}

// ---- UEp[n][256] bf16: U0 at col 0..99, U1 at col 128..227 ----
// 2-kk register blocking: thread t<100 owns cols t (U0) and t+100 (U1):
// 8 LDS b128 reads per d now feed 64 FMAs (was 32) -> LDS-pipe load halved.
__global__ __launch_bounds__(128) void k_U(const float* __restrict__ ent, const float* __restrict__ Wpt,
                                           u16* __restrict__ UEp){
  __shared__ float sh[DIM][36];
  int n0 = blockIdx.x*32;         // 3125*32 = 100000
  for (int idx=threadIdx.x; idx<32*DIM; idx+=128){
    int n = idx/DIM, d = idx%DIM;
    sh[d][n] = ent[(size_t)(n0+n)*DIM + d];
  }
  __syncthreads();
  int kk = threadIdx.x;
  if (kk >= DIM) return;
  float acc0[32], acc1[32];
  #pragma unroll
  for (int i=0;i<32;i++){ acc0[i]=0.f; acc1[i]=0.f; }
  for (int d=0;d<DIM;d++){
    float w0 = Wpt[d*200+kk];
    float w1 = Wpt[d*200+kk+100];
    #pragma unroll
    for (int ib=0;ib<8;ib++){
      float4 s4 = *(const float4*)&sh[d][ib*4];
      acc0[ib*4+0] += w0*s4.x;  acc1[ib*4+0] += w1*s4.x;
      acc0[ib*4+1] += w0*s4.y;  acc1[ib*4+1] += w1*s4.y;
      acc0[ib*4+2] += w0*s4.z;  acc1[ib*4+2] += w1*s4.z;
      acc0[ib*4+3] += w0*s4.w;  acc1[ib*4+3] += w1*s4.w;
    }
  }
  for (int i=0;i<32;i++){
    u16* row = UEp + (size_t)(n0+i)*PITCH;
    row[kk]       = f2bf(acc0[i]);
    row[128+kk]   = f2bf(acc1[i]);
  }
}

// ---- bn1 stats over 2E rows of c_pre (edge sweep, 2-edge unrolled) ----
__global__ __launch_bounds__(256) void k_cstats(const int* __restrict__ trip,
    const u16* __restrict__ UEp, const float* __restrict__ V, const float* __restrict__ bp,
    float* __restrict__ Sc, float* __restrict__ Sc2){
  __shared__ float scB[DIM], sc2B[DIM];
  for (int i=threadIdx.x;i<DIM;i+=256){ scB[i]=0.f; sc2B[i]=0.f; }
  __syncthreads();
  int lane = threadIdx.x & 31;
  int slot = (blockIdx.x*256 + threadIdx.x) >> 5;
  int nslots = gridDim.x*8;
  bool act = lane < 25;
  int dbase = lane*4;
  float bpv[4]={0,0,0,0};
  if (act) ld4f(bp+dbase, bpv);
  float sc[4]={0,0,0,0}, sc2[4]={0,0,0,0};
  int e = slot;
  for (; e + nslots < E_EDGES; e += 2*nslots){
    int3 ta = ((const int3*)trip)[e];
    int3 tb = ((const int3*)trip)[e+nslots];
    if (act){
      const u16* rxa = UEp + (size_t)ta.x*PITCH;
      const u16* rya = UEp + (size_t)ta.y*PITCH;
      const u16* rxb = UEp + (size_t)tb.x*PITCH;
      const u16* ryb = UEp + (size_t)tb.y*PITCH;
      float Pa[4],Qa[4],Ra[4],Sa[4],Va[4];
      float Pb[4],Qb[4],Rb[4],Sb[4],Vb[4];
      ld4a(rxa+dbase, Pa);      ld4a(rya+128+dbase, Qa);
      ld4a(rya+dbase, Ra);      ld4a(rxa+128+dbase, Sa);
      ld4a(rxb+dbase, Pb);      ld4a(ryb+128+dbase, Qb);
      ld4a(ryb+dbase, Rb);      ld4a(rxb+128+dbase, Sb);
      ld4f(V+(size_t)ta.z*DIM+dbase, Va);
      ld4f(V+(size_t)tb.z*DIM+dbase, Vb);
      #pragma unroll
      for (int i=0;i<4;i++){
        float cfa = Pa[i]+Qa[i]+Va[i]+bpv[i];
        float cia = Ra[i]+Sa[i]-Va[i]+bpv[i];
        float cfb = Pb[i]+Qb[i]+Vb[i]+bpv[i];
        float cib = Rb[i]+Sb[i]-Vb[i]+bpv[i];
        sc[i]  += (cfa+cia) + (cfb+cib);
        sc2[i] += cfa*cfa + cia*cia + cfb*cfb + cib*cib;
      }
    }
  }
  for (; e < E_EDGES; e += nslots){
    int3 t = ((const int3*)trip)[e];
    if (act){
      const u16* rx = UEp + (size_t)t.x*PITCH;
      const u16* ry = UEp + (size_t)t.y*PITCH;
      float P[4],Q[4],R[4],S[4],Vv[4];
      ld4a(rx+dbase, P);
      ld4a(ry+128+dbase, Q);
      ld4a(ry+dbase, R);
      ld4a(rx+128+dbase, S);
      ld4f(V+(size_t)t.z*DIM+dbase, Vv);
      #pragma unroll
      for (int i=0;i<4;i++){
        float cf = P[i]+Q[i]+Vv[i]+bpv[i];
        float ci = R[i]+S[i]-Vv[i]+bpv[i];
        sc[i]  += cf+ci;
        sc2[i] += cf*cf + ci*ci;
      }
    }
  }
  if (act){
    #pragma unroll
    for (int i=0;i<4;i++){ atomicAdd(&scB[dbase+i], sc[i]); atomicAdd(&sc2B[dbase+i], sc2[i]); }
  }
  __syncthreads();
  for (int i=threadIdx.x;i<DIM;i+=256){ atomicAdd(&Sc[i], scB[i]); atomicAdd(&Sc2[i], sc2B[i]); }
}

// ---- bn1 affine + attention vector w + scalar C ----
__global__ void k_bn1x(const float* __restrict__ g1, const float* __restrict__ b1,
                       const float* __restrict__ Sc, const float* __restrict__ Sc2,
                       const float* __restrict__ bp, const float* __restrict__ a2W, const float* __restrict__ a2b,
                       float* __restrict__ scale1, float* __restrict__ shift1,
                       float* __restrict__ wvec, float* __restrict__ consts){
  __shared__ float red[128];
  int k = threadIdx.x;            // 128
  float contrib = 0.f;
  if (k < DIM){
    float mean = Sc[k]*(1.0f/TWO_E);
    float var  = Sc2[k]*(1.0f/TWO_E) - mean*mean;
    float s = g1[k] * rsqrtf(var + BN_EPS);
    float sh = b1[k] - mean*s;
    float a2 = a2W[k];
    scale1[k] = s;
    shift1[k] = sh;
    float wv = s*a2;
    wvec[k] = wv;
    contrib = bp[k]*wv + sh*a2;
  }
  red[k] = contrib;
  __syncthreads();
  for (int m=64;m>=1;m>>=1){ if (k<m) red[k]+=red[k+m]; __syncthreads(); }
  if (k==0) consts[0] = red[0] + a2b[0];
}

// ---- phi0[n]=U0[n].w, phi1[n]=U1[n].w ----
__global__ __launch_bounds__(256) void k_phi(const u16* __restrict__ UEp, const float* __restrict__ wvec,
                                             float* __restrict__ phi0, float* __restrict__ phi1){
  int lane = threadIdx.x & 31;
  int n = blockIdx.x*8 + (threadIdx.x>>5);
  bool act = lane < 25;
  int dbase = lane*4;
  float w4[4]={0,0,0,0};
  float p0=0.f, p1=0.f;
  if (act){
    ld4f(wvec+dbase, w4);
    float P[4], Q[4];
    ld4a(UEp + (size_t)n*PITCH + dbase, P);
    ld4a(UEp + (size_t)n*PITCH + 128 + dbase, Q);
    #pragma unroll
    for (int i=0;i<4;i++){ p0 += P[i]*w4[i]; p1 += Q[i]*w4[i]; }
  }
  #pragma unroll
  for (int m=16;m>=1;m>>=1){ p0 += __shfl_xor(p0,m,32); p1 += __shfl_xor(p1,m,32); }
  if (lane==0){ phi0[n]=p0; phi1[n]=p1; }
}

// ---- psi[r]=V[r].w ----
__global__ void k_psi(const float* __restrict__ V, const float* __restrict__ wvec, float* __restrict__ psi){
  __shared__ float w[DIM];
  int t = threadIdx.x;            // 256
  if (t < DIM) w[t] = wvec[t];
  __syncthreads();
  if (t >= NREL) return;
  float s=0.f;
  for (int k=0;k<DIM;k++) s += V[t*DIM+k]*w[k];
  psi[t] = s;
}

// ---- entity aggregation: one 32-lane slot per entity, 2-edge unrolled ----
__global__ __launch_bounds__(256) void k_aggr_ent(const u32* __restrict__ offs, const u32* __restrict__ inc,
    const u16* __restrict__ UEp, const float* __restrict__ V,
    const float* __restrict__ phi0, const float* __restrict__ phi1, const float* __restrict__ psi,
    const float* __restrict__ consts, const float* __restrict__ bp,
    const float* __restrict__ scale1, const float* __restrict__ shift1,
    float* __restrict__ out){
  int lane = threadIdx.x & 31;
  int n = blockIdx.x*8 + (threadIdx.x>>5);
  bool act = lane < 25;
  int dbase = lane*4;
  u32 o0 = offs[n], o1 = offs[n+1];
  float C = consts[0];
  float p0n = phi0[n];
  float acc[4]={0,0,0,0};
  float wsum=0.f;
  u32 i = o0;
  for (; i+2 <= o1; i += 2){
    u32 pk0 = inc[i], pk1 = inc[i+1];
    u32 oth0 = pk0 & 0x1FFFFu,      oth1 = pk1 & 0x1FFFFu;
    u32 rr0  = (pk0>>17) & 0xFFu,   rr1  = (pk1>>17) & 0xFFu;
    float sg0 = (pk0>>25)? -1.f:1.f, sg1 = (pk1>>25)? -1.f:1.f;
    float ph0 = phi1[oth0], ph1 = phi1[oth1];
    float ps0 = psi[rr0],   ps1 = psi[rr1];
    float B0[4],V0[4],B1[4],V1[4];
    if (act){
      ld4a(UEp + (size_t)oth0*PITCH + 128 + dbase, B0);
      ld4a(UEp + (size_t)oth1*PITCH + 128 + dbase, B1);
      ld4f(V + (size_t)rr0*DIM + dbase, V0);
      ld4f(V + (size_t)rr1*DIM + dbase, V1);
    }
    float t0 = p0n + ph0 + sg0*ps0 + C;
    float t1 = p0n + ph1 + sg1*ps1 + C;
    float w0 = ewt(t0), w1 = ewt(t1);
    wsum += w0+w1;
    if (act){
      #pragma unroll
      for (int j=0;j<4;j++) acc[j] += w0*(B0[j]+sg0*V0[j]) + w1*(B1[j]+sg1*V1[j]);
    }
  }
  if (i < o1){
    u32 pk = inc[i];
    u32 oth = pk & 0x1FFFFu;
    u32 rr = (pk>>17) & 0xFFu;
    float sg = (pk>>25)? -1.f:1.f;
    float t = p0n + phi1[oth] + sg*psi[rr] + C;
    float w = ewt(t);
    wsum += w;
    if (act){
      float B[4], Vv[4];
      ld4a(UEp + (size_t)oth*PITCH + 128 + dbase, B);
      ld4f(V + (size_t)rr*DIM + dbase, Vv);
      #pragma unroll
      for (int j=0;j<4;j++) acc[j] += w*(B[j]+sg*Vv[j]);
    }
  }
  if (act){
    float o4[4];
    if (o1 == o0){
      o4[0]=o4[1]=o4[2]=o4[3]=0.f;
    } else {
      float P[4], bp4[4], s14[4], sh4[4];
      ld4a(UEp + (size_t)n*PITCH + dbase, P);
      ld4f(bp+dbase, bp4);
      ld4f(scale1+dbase, s14);
      ld4f(shift1+dbase, sh4);
      float inv = __frcp_rn(wsum);
      #pragma unroll
      for (int j=0;j<4;j++){
        float v = (P[j]+bp4[j])*s14[j] + sh4[j] + s14[j]*acc[j]*inv;
        o4[j] = eluf(v);
      }
    }
    *(float4*)(out + (size_t)n*DIM + dbase) = make_float4(o4[0],o4[1],o4[2],o4[3]);
  }
}

// ---- rel aggregation: NREL*RSEG blocks, 2-edge unrolled, LDS reduce + atomic burst ----
__global__ __launch_bounds__(256) void k_aggr_relP(
    const u32* __restrict__ roff, const u64* __restrict__ rele64,
    const u16* __restrict__ UEp, const float* __restrict__ V,
    const float* __restrict__ phi0, const float* __restrict__ phi1, const float* __restrict__ psi,
    const float* __restrict__ consts, const float* __restrict__ bp,
    const float* __restrict__ scale1, const float* __restrict__ shift1,
    float* __restrict__ relacc){
  __shared__ float red[8][104];
  int r   = blockIdx.x / RSEG;
  int seg = blockIdx.x % RSEG;
  int lane = threadIdx.x & 31;
  int slot = threadIdx.x >> 5;    // 8 slots
  bool act = lane < 25;
  int dbase = lane*4;
  float C = consts[0];
  float psir = psi[r];
  float bp4[4]={0,0,0,0}, s14[4]={0,0,0,0}, sh4[4]={0,0,0,0}, Vv[4]={0,0,0,0};
  if (act){
    ld4f(bp+dbase, bp4);
    ld4f(scale1+dbase, s14);
    ld4f(shift1+dbase, sh4);
    ld4f(V + (size_t)r*DIM + dbase, Vv);
  }
  u32 q0 = roff[r], q1 = roff[r+1];
  float acc[4]={0,0,0,0};
  for (u32 q = q0 + (u32)(seg*8+slot)*2; q < q1; q += (u32)(RSEG*8*2)){
    u64 pk0 = rele64[q];
    bool has1 = (q+1 < q1);
    u64 pk1 = has1 ? rele64[q+1] : pk0;
    u32 a0 = (u32)(pk0 & 0x1FFFFu), b0 = (u32)((pk0>>17) & 0x1FFFFu);
    u32 a1 = (u32)(pk1 & 0x1FFFFu), b1 = (u32)((pk1>>17) & 0x1FFFFu);
    float P0[4],Q0[4],R0[4],S0[4],P1[4],Q1[4],R1[4],S1[4];
    if (act){
      const u16* rx0 = UEp + (size_t)a0*PITCH;
      const u16* ry0 = UEp + (size_t)b0*PITCH;
      const u16* rx1 = UEp + (size_t)a1*PITCH;
      const u16* ry1 = UEp + (size_t)b1*PITCH;
      ld4a(rx0+dbase, P0);      ld4a(ry0+128+dbase, Q0);
      ld4a(ry0+dbase, R0);      ld4a(rx0+128+dbase, S0);
      ld4a(rx1+dbase, P1);      ld4a(ry1+128+dbase, Q1);
      ld4a(ry1+dbase, R1);      ld4a(rx1+128+dbase, S1);
    }
    float tf0 = phi0[a0] + phi1[b0] + psir + C;
    float ti0 = phi0[b0] + phi1[a0] - psir + C;
    float tf1 = phi0[a1] + phi1[b1] + psir + C;
    float ti1 = phi0[b1] + phi1[a1] - psir + C;
    float m1 = has1 ? 1.f : 0.f;
    float ef0 = ewt(tf0), ei0 = ewt(ti0);
    float ef1 = m1*ewt(tf1), ei1 = m1*ewt(ti1);
    if (act){
      #pragma unroll
      for (int j=0;j<4;j++){
        float cf0 = (P0[j]+Q0[j]+Vv[j]+bp4[j])*s14[j] + sh4[j];
        float ci0 = (R0[j]+S0[j]-Vv[j]+bp4[j])*s14[j] + sh4[j];
        float cf1 = (P1[j]+Q1[j]+Vv[j]+bp4[j])*s14[j] + sh4[j];
        float ci1 = (R1[j]+S1[j]-Vv[j]+bp4[j])*s14[j] + sh4[j];
        acc[j] += ef0*cf0 - ei0*ci0 + ef1*cf1 - ei1*ci1;
      }
    }
  }
  if (act){
    #pragma unroll
    for (int j=0;j<4;j++) red[slot][dbase+j] = acc[j];
  }
  __syncthreads();
  int k = threadIdx.x;
  if (k < DIM){
    float s = 0.f;
    #pragma unroll
    for (int sl=0;sl<8;sl++) s += red[sl][k];
    atomicAdd(&relacc[(size_t)r*DIM + k], s);
  }
}

// ---- finalize h_rel ----
__global__ void k_out_rel(const float* __restrict__ relacc, const float* __restrict__ relcnt,
                          float* __restrict__ out){
  int idx = blockIdx.x*256 + threadIdx.x;
  if (idx >= NREL*DIM) return;
  int r = idx/DIM;
  float cn = relcnt[r]; if (cn < 1.f) cn = 1.f;
  out[(size_t)NENT*DIM + idx] = eluf(relacc[idx]/cn);
}

extern "C" void kernel_launch(void* const* d_in, const int* in_sizes, int n_in,
                              void* d_out, int out_size, void* d_ws, size_t ws_size,
                              hipStream_t stream){
  const int*   trip = (const int*)d_in[0];
  const float* ent  = (const float*)d_in[1];
  const float* rel  = (const float*)d_in[2];
  const float* aW   = (const float*)d_in[3];
  const float* ab   = (const float*)d_in[4];
  const float* a2W  = (const float*)d_in[5];
  const float* a2b  = (const float*)d_in[6];
  const float* g0   = (const float*)d_in[7];
  const float* b0   = (const float*)d_in[8];
  const float* g1   = (const float*)d_in[9];
  const float* b1   = (const float*)d_in[10];
  float* out = (float*)d_out;
  float* wsf = (float*)d_ws;
  if (ws_size < TOTAL_F*sizeof(float)) return;
  u16* UEp  = (u16*)(wsf + OFF_UE);
  u32* deg  = (u32*)(wsf + OFF_DEG);
  u32* cur  = (u32*)(wsf + OFF_CUR);
  u32* offs = (u32*)(wsf + OFF_OFFS);
  u32* roff = (u32*)(wsf + OFF_ROFF);
  u32* bhist= (u32*)(wsf + OFF_BHIST);
  u32* rbase= (u32*)(wsf + OFF_RBASE);
  u32* part = (u32*)(wsf + OFF_PART);
  u32* base = (u32*)(wsf + OFF_BASE);
  u32* rtot = (u32*)(wsf + OFF_RTOT);
  u32* inc  = (u32*)(wsf + OFF_INC);
  u64* rele = (u64*)(wsf + OFF_RELE64);

  hipMemsetAsync(d_ws, 0, ZERO_END*sizeof(float), stream);

  k_histA<<<dim3(NB), dim3(256), 0, stream>>>(trip, deg, bhist);
  k_entstats<<<dim3(1024), dim3(256), 0, stream>>>(ent, deg, wsf+OFF_S1, wsf+OFF_S2);
  k_scanA<<<dim3(256), dim3(256), 0, stream>>>(deg, part);
  k_scanR<<<dim3(NREL), dim3(256), 0, stream>>>(bhist, rbase, rtot);
  k_scanB<<<dim3(1), dim3(256), 0, stream>>>(part, base, offs, rtot, roff, wsf+OFF_RELCNTF);
  k_scanC<<<dim3(256), dim3(256), 0, stream>>>(deg, base, offs);
  k_relstats<<<dim3(1), dim3(128), 0, stream>>>(rel, wsf+OFF_RELCNTF, wsf+OFF_S2R);
  k_scale0<<<dim3(1), dim3(320), 0, stream>>>(g0, b0, wsf+OFF_S1, wsf+OFF_S2, wsf+OFF_S2R,
                                              wsf+OFF_SCALE0, wsf+OFF_SHIFT0);
  k_foldW<<<dim3(118), dim3(256), 0, stream>>>(aW, wsf+OFF_SCALE0, wsf+OFF_WPT, wsf+OFF_WRELT);
  k_bp<<<dim3(100), dim3(64), 0, stream>>>(aW, ab, wsf+OFF_SHIFT0, wsf+OFF_BP);
  k_V<<<dim3(NREL), dim3(128), 0, stream>>>(rel, wsf+OFF_WRELT, wsf+OFF_V);
  k_U<<<dim3(NENT/32), dim3(128), 0, stream>>>(ent, wsf+OFF_WPT, UEp);
  k_incB<<<dim3(NB), dim3(256), 0, stream>>>(trip, offs, cur, roff, rbase, inc, rele);
  k_cstats<<<dim3(2048), dim3(256), 0, stream>>>(trip, UEp, wsf+OFF_V, wsf+OFF_BP,
                                                 wsf+OFF_SC, wsf+OFF_SC2);
  k_bn1x<<<dim3(1), dim3(128), 0, stream>>>(g1, b1, wsf+OFF_SC, wsf+OFF_SC2, wsf+OFF_BP, a2W, a2b,
                                            wsf+OFF_SCALE1, wsf+OFF_SHIFT1, wsf+OFF_WVEC, wsf+OFF_CONST);
  k_phi<<<dim3(NENT/8), dim3(256), 0, stream>>>(UEp, wsf+OFF_WVEC, wsf+OFF_PHI0, wsf+OFF_PHI1);
  k_psi<<<dim3(1), dim3(256), 0, stream>>>(wsf+OFF_V, wsf+OFF_WVEC, wsf+OFF_PSI);
  k_aggr_ent<<<dim3(NENT/8), dim3(256), 0, stream>>>(offs, inc, UEp, wsf+OFF_V,
                                                     wsf+OFF_PHI0, wsf+OFF_PHI1, wsf+OFF_PSI,
                                                     wsf+OFF_CONST, wsf+OFF_BP,
                                                     wsf+OFF_SCALE1, wsf+OFF_SHIFT1, out);
  k_aggr_relP<<<dim3(NREL*RSEG), dim3(256), 0, stream>>>(roff, rele, UEp, wsf+OFF_V,
                                                   wsf+OFF_PHI0, wsf+OFF_PHI1, wsf+OFF_PSI,
                                                   wsf+OFF_CONST, wsf+OFF_BP,
                                                   wsf+OFF_SCALE1, wsf+OFF_SHIFT1,
                                                   wsf+OFF_RELACC);
  k_out_rel<<<dim3((NREL*DIM+255)/256), dim3(256), 0, stream>>>(wsf+OFF_RELACC, wsf+OFF_RELCNTF, out);
}